// Round 1
// baseline (1948.887 us; speedup 1.0000x reference)
//
#include <hip/hip_runtime.h>
#include <cfloat>
#include <math.h>

#define NB 8
#define NPT 4096
#define NC 64
#define KNN 20
#define KSZ 16

// ---------- helpers ----------
__device__ __forceinline__ unsigned short f2bf(float f) {
  unsigned u = __float_as_uint(f);
  unsigned r = (u + 0x7fffu + ((u >> 16) & 1u)) >> 16;
  return (unsigned short)r;
}
__device__ __forceinline__ float bf2f(unsigned short h) {
  return __uint_as_float(((unsigned)h) << 16);
}

// ---------- K0a: conv_w [64][2048] -> cwt [2048][64] ----------
__global__ void k_transpose_cw(const float* __restrict__ cw, float* __restrict__ cwt) {
  int t = blockIdx.x * 256 + threadIdx.x;   // 131072 total
  int o = t & 63, j = t >> 6;
  cwt[j * 64 + o] = cw[o * 2048 + j];
}

// ---------- K0b: feature [B][C][N] -> ftT [B][N][C] ----------
__global__ void k_transpose_ft(const float* __restrict__ f, float* __restrict__ ft) {
  __shared__ float tile[64][65];
  int b = blockIdx.x >> 6;
  int n0 = (blockIdx.x & 63) * 64;
  int lane = threadIdx.x & 63;
  int rr = threadIdx.x >> 6;  // 0..3
#pragma unroll
  for (int c0 = 0; c0 < 64; c0 += 4) {
    int c = c0 + rr;
    tile[c][lane] = f[(b * 64 + c) * 4096 + n0 + lane];
  }
  __syncthreads();
#pragma unroll
  for (int m0 = 0; m0 < 64; m0 += 4) {
    int nn = m0 + rr;
    ft[(b * 4096 + n0 + nn) * 64 + lane] = tile[lane][nn];
  }
}

// ---------- K1: KNN ----------
// One row per lane-pair: even lane scans candidates [0,2048), odd [2048,4096).
// Each keeps f32 top-24; merge via shfl; even lane re-ranks 24 in f64 and
// writes the exact top-20 set (self forced to slot 0).
__global__ void k_knn(const float* __restrict__ x, int* __restrict__ idxOut) {
  __shared__ float xs[4096], ys[4096], zs[4096];
  int b = blockIdx.x >> 5;
  int base = (blockIdx.x & 31) * 128;
  const float* xb = x + b * 3 * 4096;
  for (int i = threadIdx.x; i < 4096; i += 256) {
    xs[i] = xb[i];
    ys[i] = xb[4096 + i];
    zs[i] = xb[8192 + i];
  }
  __syncthreads();

  int n = base + (threadIdx.x >> 1);
  int half = threadIdx.x & 1;
  float qx = xs[n], qy = ys[n], qz = zs[n];

  float v[24];
  int id[24];
#pragma unroll
  for (int j = 0; j < 24; ++j) { v[j] = FLT_MAX; id[j] = -1; }

  int j0 = half * 2048;
  for (int j = j0; j < j0 + 2048; ++j) {
    float dx = xs[j] - qx, dy = ys[j] - qy, dz = zs[j] - qz;
    float d2 = fmaf(dx, dx, fmaf(dy, dy, dz * dz));
    if (d2 < v[23]) {
#pragma unroll
      for (int r = 23; r >= 1; --r) {
        bool c1 = d2 < v[r - 1];
        bool c2 = d2 < v[r];
        float nv = c1 ? v[r - 1] : (c2 ? d2 : v[r]);
        int ni = c1 ? id[r - 1] : (c2 ? j : id[r]);
        v[r] = nv;
        id[r] = ni;
      }
      bool c0 = d2 < v[0];
      v[0] = c0 ? d2 : v[0];
      id[0] = c0 ? j : id[0];
    }
  }

  // exchange with partner lane
  float pv[24];
  int pid[24];
#pragma unroll
  for (int j = 0; j < 24; ++j) {
    pv[j] = __shfl_xor(v[j], 1, 64);
    pid[j] = __shfl_xor(id[j], 1, 64);
  }

  if (half == 0) {
    // merge partner list into mine (both sorted ascending)
#pragma unroll
    for (int j = 0; j < 24; ++j) {
      float d2 = pv[j];
      int ii = pid[j];
      if (d2 < v[23]) {
#pragma unroll
        for (int r = 23; r >= 1; --r) {
          bool c1 = d2 < v[r - 1];
          bool c2 = d2 < v[r];
          float nv = c1 ? v[r - 1] : (c2 ? d2 : v[r]);
          int ni = c1 ? id[r - 1] : (c2 ? ii : id[r]);
          v[r] = nv;
          id[r] = ni;
        }
        bool c0 = d2 < v[0];
        v[0] = c0 ? d2 : v[0];
        id[0] = c0 ? ii : id[0];
      }
    }
    // f64 exact re-rank of the 24 survivors; drop the 4 largest
    // (ties: drop the higher original index, matching top_k keep-lowest)
    double dqx = (double)qx, dqy = (double)qy, dqz = (double)qz;
    double dv[24];
#pragma unroll
    for (int j = 0; j < 24; ++j) {
      int ii = id[j];
      double dx = (double)xs[ii] - dqx;
      double dy = (double)ys[ii] - dqy;
      double dz = (double)zs[ii] - dqz;
      dv[j] = dx * dx + dy * dy + dz * dz;
    }
    unsigned dead = 0u;
    for (int r = 0; r < 4; ++r) {
      double best = -1.0;
      int bj = 0, bidx = -1;
#pragma unroll
      for (int j = 0; j < 24; ++j) {
        bool alive = ((dead >> j) & 1u) == 0u;
        bool better = alive && (dv[j] > best || (dv[j] == best && id[j] > bidx));
        if (better) { best = dv[j]; bj = j; bidx = id[j]; }
      }
      dead |= (1u << bj);
    }
    int g = b * 4096 + n;
    idxOut[g * 20] = n;  // self first
    int pos = 1;
#pragma unroll
    for (int j = 0; j < 24; ++j) {
      bool keep = (((dead >> j) & 1u) == 0u) && (id[j] != n);
      if (keep) { idxOut[g * 20 + pos] = id[j]; pos++; }
    }
  }
}

// ---------- K2: fused geometric features + aw + agg + conv ----------
// Block = 512 threads = 8 waves; wave p handles point p of the block's 8 points.
__launch_bounds__(512)
__global__ void k_main(const float* __restrict__ x, const float* __restrict__ feat,
                       const float* __restrict__ ftT, int useFtT,
                       const float* __restrict__ kern, const float* __restrict__ mlp_w,
                       const float* __restrict__ mlp_b, const float* __restrict__ cwt,
                       const float* __restrict__ conv_b, const int* __restrict__ idxIn,
                       float* __restrict__ out) {
  __shared__ __align__(16) unsigned short agg[8][2048];  // bf16 agg, also reused as f32 reduce scratch
  __shared__ float awL[8][20][16];
  __shared__ float f7L[8][20][7];
  __shared__ int idxL[8][20];

  int t = threadIdx.x;
  int p = t >> 6, lane = t & 63;
  int g = blockIdx.x * 8 + p;
  int b = g >> 12, n = g & 4095;
  const float* xb = x + b * 3 * 4096;

  // step 0: per-neighbor geometry + raw aw rows (lanes 0..19 of each wave)
  if (lane < 20) {
    int kk = idxIn[g * 20 + lane];
    idxL[p][lane] = kk;
    float qx = xb[n], qy = xb[4096 + n], qz = xb[8192 + n];
    float cx = xb[kk], cy = xb[4096 + kk], cz = xb[8192 + kk];
    float rx = cx - qx, ry = cy - qy, rz = cz - qz;
    float ds = sqrtf(rx * rx + ry * ry + rz * rz);
    f7L[p][lane][0] = qx;
    f7L[p][lane][1] = qy;
    f7L[p][lane][2] = qz;
    f7L[p][lane][3] = rx;
    f7L[p][lane][4] = ry;
    f7L[p][lane][5] = rz;
    f7L[p][lane][6] = ds;
#pragma unroll
    for (int s = 0; s < 16; ++s) {
      float dot = rx * kern[s] + ry * kern[16 + s] + rz * kern[32 + s];
      if (lane == 0 && s == 0) dot += 1.0f;
      awL[p][lane][s] = dot > 0.0f ? dot : 0.0f;
    }
  }
  __syncthreads();

  // step 1: aw normalization chain (128 threads: one per (point, s))
  if (t < 128) {
    int pp = t >> 4, s = t & 15;
    float sum = 0.0f;
#pragma unroll
    for (int k = 0; k < 20; ++k) sum += awL[pp][k][s];
    float inv1 = 1.0f / (sum + 1e-6f);
    float sum2 = 0.0f;
#pragma unroll
    for (int k = 0; k < 20; ++k) {
      float w = awL[pp][k][s] * inv1;
      sum2 += w * w;
    }
    float inv2 = 1.0f / (sum2 + 1e-6f);
#pragma unroll
    for (int k = 0; k < 20; ++k) {
      float w = awL[pp][k][s] * inv1;
      w = w * w * inv2;
      awL[pp][k][s] = (w > 0.1f) ? w : 0.0f;
    }
  }
  __syncthreads();

  // step 2: agg build. thread (p, c=lane) owns spiral row c and x_feats row c.
  {
    int c = lane;
    float fv[20];
    if (useFtT) {
#pragma unroll
      for (int k = 0; k < 20; ++k) fv[k] = ftT[(b * 4096 + idxL[p][k]) * 64 + c];
    } else {
      const float* fb = feat + (b * 64 + c) * 4096;
#pragma unroll
      for (int k = 0; k < 20; ++k) fv[k] = fb[idxL[p][k]];
    }
    float mw[7];
#pragma unroll
    for (int j = 0; j < 7; ++j) mw[j] = mlp_w[c * 7 + j];
    float mb = mlp_b[c];
    float xf[20];
#pragma unroll
    for (int k = 0; k < 20; ++k) {
      float s = mb;
#pragma unroll
      for (int j = 0; j < 7; ++j) s = fmaf(mw[j], f7L[p][k][j], s);
      xf[k] = s;
    }
    float acc1[16], acc2[16];
#pragma unroll
    for (int s = 0; s < 16; ++s) { acc1[s] = 0.0f; acc2[s] = 0.0f; }
#pragma unroll
    for (int k = 0; k < 20; ++k) {
      float a = fv[k], bx = xf[k];
#pragma unroll
      for (int s = 0; s < 16; ++s) {
        float w = awL[p][k][s];
        acc1[s] = fmaf(a, w, acc1[s]);
        acc2[s] = fmaf(bx, w, acc2[s]);
      }
    }
#pragma unroll
    for (int s = 0; s < 16; ++s) {
      agg[p][c * 16 + s] = f2bf(acc1[s]);
      agg[p][(64 + c) * 16 + s] = f2bf(acc2[s]);
    }
  }
  __syncthreads();

  // phase B: out[p][o] = conv_b[o] + sum_j cwt[j][o] * agg[p][j]
  // thread: og = t&15 (4 outputs), slice = t>>4 (32 j-slices of 64)
  int og = t & 15, slice = t >> 4;
  const float4* cwt4 = (const float4*)cwt;
  float acc[8][4];
#pragma unroll
  for (int pp = 0; pp < 8; ++pp)
#pragma unroll
    for (int q = 0; q < 4; ++q) acc[pp][q] = 0.0f;

  for (int jj = 0; jj < 64; ++jj) {
    int j = slice * 64 + jj;
    float4 w4 = cwt4[j * 16 + og];
#pragma unroll
    for (int pp = 0; pp < 8; ++pp) {
      float a = bf2f(agg[pp][j]);
      acc[pp][0] = fmaf(a, w4.x, acc[pp][0]);
      acc[pp][1] = fmaf(a, w4.y, acc[pp][1]);
      acc[pp][2] = fmaf(a, w4.z, acc[pp][2]);
      acc[pp][3] = fmaf(a, w4.w, acc[pp][3]);
    }
  }
  // reduce the 4 slices within each wave (lane bits 4,5)
#pragma unroll
  for (int pp = 0; pp < 8; ++pp)
#pragma unroll
    for (int q = 0; q < 4; ++q) {
      acc[pp][q] += __shfl_xor(acc[pp][q], 16, 64);
      acc[pp][q] += __shfl_xor(acc[pp][q], 32, 64);
    }
  __syncthreads();  // all agg reads done; safe to reuse LDS
  float* red = (float*)&agg[0][0];  // 16KB needed, 32KB available
  int w = t >> 6;
  if (((t >> 4) & 3) == 0) {
#pragma unroll
    for (int pp = 0; pp < 8; ++pp)
#pragma unroll
      for (int q = 0; q < 4; ++q)
        red[((w * 16 + og) * 8 + pp) * 4 + q] = acc[pp][q];
  }
  __syncthreads();
  // final cross-wave reduce + write: thread t -> (p = t>>6, o = t&63)
  {
    int pp = t >> 6, o = t & 63;
    float s = conv_b[o];
#pragma unroll
    for (int ww = 0; ww < 8; ++ww)
      s += red[((ww * 16 + (o >> 2)) * 8 + pp) * 4 + (o & 3)];
    int gg = blockIdx.x * 8 + pp;
    int bb = gg >> 12, nn = gg & 4095;
    out[(bb * 64 + o) * 4096 + nn] = s;
  }
}

// ---------- K3a: BN stats (one block per channel) ----------
__global__ void k_bnstats(const float* __restrict__ out, const float* __restrict__ gamma,
                          const float* __restrict__ beta, float* __restrict__ stats) {
  __shared__ double rs[256], rq[256];
  int o = blockIdx.x;
  double s = 0.0, q = 0.0;
  for (int b = 0; b < 8; ++b) {
    const float* p = out + (b * 64 + o) * 4096;
    for (int i = threadIdx.x; i < 4096; i += 256) {
      double v = (double)p[i];
      s += v;
      q += v * v;
    }
  }
  rs[threadIdx.x] = s;
  rq[threadIdx.x] = q;
  __syncthreads();
  for (int st = 128; st > 0; st >>= 1) {
    if ((int)threadIdx.x < st) {
      rs[threadIdx.x] += rs[threadIdx.x + st];
      rq[threadIdx.x] += rq[threadIdx.x + st];
    }
    __syncthreads();
  }
  if (threadIdx.x == 0) {
    double mean = rs[0] / 32768.0;
    double var = rq[0] / 32768.0 - mean * mean;
    double inv = 1.0 / sqrt(var + 1e-5);
    double sc = (double)gamma[o] * inv;
    stats[o * 2] = (float)sc;
    stats[o * 2 + 1] = (float)((double)beta[o] - mean * sc);
  }
}

// ---------- K3b: BN apply (in place) ----------
__global__ void k_bnapply(float* __restrict__ out, const float* __restrict__ stats) {
  int i = blockIdx.x * 256 + threadIdx.x;
  int o = (i >> 12) & 63;
  out[i] = fmaf(out[i], stats[o * 2], stats[o * 2 + 1]);
}

extern "C" void kernel_launch(void* const* d_in, const int* in_sizes, int n_in,
                              void* d_out, int out_size, void* d_ws, size_t ws_size,
                              hipStream_t stream) {
  const float* x = (const float*)d_in[0];
  const float* feat = (const float*)d_in[1];
  const float* kern = (const float*)d_in[2];
  const float* mlp_w = (const float*)d_in[3];
  const float* mlp_b = (const float*)d_in[4];
  const float* conv_w = (const float*)d_in[5];
  const float* conv_b = (const float*)d_in[6];
  const float* gamma = (const float*)d_in[7];
  const float* beta = (const float*)d_in[8];
  float* out = (float*)d_out;
  char* ws = (char*)d_ws;

  // workspace layout
  int* idx = (int*)ws;                          // 32768*20*4      = 2,621,440
  float* stats = (float*)(ws + 2621440);        // 64*2*4          = 512 (padded)
  float* cwt = (float*)(ws + 2625536);          // 2048*64*4       = 524,288
  float* ftT = (float*)(ws + 3149824);          // 8*4096*64*4     = 8,388,608
  int useFtT = (ws_size >= (size_t)(3149824 + 8388608)) ? 1 : 0;

  k_transpose_cw<<<512, 256, 0, stream>>>(conv_w, cwt);
  if (useFtT) k_transpose_ft<<<512, 256, 0, stream>>>(feat, ftT);
  k_knn<<<256, 256, 0, stream>>>(x, idx);
  k_main<<<4096, 512, 0, stream>>>(x, feat, ftT, useFtT, kern, mlp_w, mlp_b, cwt,
                                   conv_b, idx, out);
  k_bnstats<<<64, 256, 0, stream>>>(out, gamma, beta, stats);
  k_bnapply<<<8192, 256, 0, stream>>>(out, stats);
}

// Round 2
// 497.699 us; speedup vs baseline: 3.9158x; 3.9158x over previous
//
#include <hip/hip_runtime.h>
#include <cfloat>
#include <math.h>

#define NB 8
#define NPT 4096
#define NC 64
#define KNN 20
#define KSZ 16

// ---------- helpers ----------
__device__ __forceinline__ unsigned short f2bf(float f) {
  unsigned u = __float_as_uint(f);
  unsigned r = (u + 0x7fffu + ((u >> 16) & 1u)) >> 16;
  return (unsigned short)r;
}
__device__ __forceinline__ float bf2f(unsigned short h) {
  return __uint_as_float(((unsigned)h) << 16);
}

// ---------- K0a: conv_w [64][2048] -> cwt [2048][64] ----------
__global__ void k_transpose_cw(const float* __restrict__ cw, float* __restrict__ cwt) {
  int t = blockIdx.x * 256 + threadIdx.x;   // 131072 total
  int o = t & 63, j = t >> 6;
  cwt[j * 64 + o] = cw[o * 2048 + j];
}

// ---------- K0b: feature [B][C][N] -> ftT [B][N][C] ----------
__global__ void k_transpose_ft(const float* __restrict__ f, float* __restrict__ ft) {
  __shared__ float tile[64][65];
  int b = blockIdx.x >> 6;
  int n0 = (blockIdx.x & 63) * 64;
  int lane = threadIdx.x & 63;
  int rr = threadIdx.x >> 6;  // 0..3
#pragma unroll
  for (int c0 = 0; c0 < 64; c0 += 4) {
    int c = c0 + rr;
    tile[c][lane] = f[(b * 64 + c) * 4096 + n0 + lane];
  }
  __syncthreads();
#pragma unroll
  for (int m0 = 0; m0 < 64; m0 += 4) {
    int nn = m0 + rr;
    ft[(b * 4096 + n0 + nn) * 64 + lane] = tile[lane][nn];
  }
}

// ---------- K1: KNN v2 ----------
// One WAVE per query row. Each lane scans 64 candidates keeping a branchless
// sorted top-M; wave-merge extracts the 24 smallest via u64-packed min-reduce;
// exact f64 re-rank keeps 20 (ties -> lower index). Safety check guarantees
// exactness; rare rows redo with M=24 (provably exact).

__device__ __forceinline__ unsigned long long wave_min_u64(unsigned long long k) {
#pragma unroll
  for (int s = 1; s < 64; s <<= 1) {
    unsigned long long o = __shfl_xor(k, s, 64);
    k = (o < k) ? o : k;
  }
  return k;
}

template <int M>
__device__ __forceinline__ bool knn_row(const float* __restrict__ xs,
                                        const float* __restrict__ ys,
                                        const float* __restrict__ zs,
                                        int n, int lane, int g, bool check,
                                        int* __restrict__ idxOut) {
  float qx = xs[n], qy = ys[n], qz = zs[n];
  float v[M];
  int id[M];
#pragma unroll
  for (int r = 0; r < M; ++r) { v[r] = FLT_MAX; id[r] = 0x7fffffff; }

#pragma unroll 4
  for (int i = 0; i < 64; ++i) {
    int j = (i << 6) | lane;
    float dx = xs[j] - qx, dy = ys[j] - qy, dz = zs[j] - qz;
    float d2 = fmaf(dx, dx, fmaf(dy, dy, dz * dz));
    bool c[M];
#pragma unroll
    for (int r = 0; r < M; ++r) c[r] = d2 < v[r];
#pragma unroll
    for (int r = M - 1; r >= 1; --r) {
      v[r] = c[r - 1] ? v[r - 1] : (c[r] ? d2 : v[r]);
      id[r] = c[r - 1] ? id[r - 1] : (c[r] ? j : id[r]);
    }
    v[0] = c[0] ? d2 : v[0];
    id[0] = c[0] ? j : id[0];
  }
  float worst = v[M - 1];

  // ---- wave merge: extract 24 smallest (key = f32bits<<32 | idx, unique) ----
  unsigned long long key = ((unsigned long long)__float_as_uint(v[0]) << 32) | (unsigned)id[0];
  unsigned long long ext = ~0ull;
  unsigned long long k = 0ull;
  for (int r = 0; r < 24; ++r) {
    k = wave_min_u64(key);
    if (lane == r) ext = k;
    if (key == k) {  // unique winner: pop head
#pragma unroll
      for (int q = 0; q < M - 1; ++q) { v[q] = v[q + 1]; id[q] = id[q + 1]; }
      v[M - 1] = FLT_MAX;
      id[M - 1] = 0x7fffffff;
      key = ((unsigned long long)__float_as_uint(v[0]) << 32) | (unsigned)id[0];
    }
  }
  if (check) {
    float t24 = __uint_as_float((unsigned)(k >> 32));
    if (__any(worst <= t24)) return false;  // some lane may have dropped a top-24 member
  }

  // ---- exact f64 re-rank of the 24, drop 4 largest (tie -> higher index) ----
  int ei = (int)(unsigned)(ext & 0xffffffffu);
  bool al = lane < 24;
  double dv = -1.0;
  if (al) {
    double dx = (double)xs[ei] - (double)qx;
    double dy = (double)ys[ei] - (double)qy;
    double dz = (double)zs[ei] - (double)qz;
    dv = dx * dx + dy * dy + dz * dz;
  }
#pragma unroll
  for (int r = 0; r < 4; ++r) {
    double bd = al ? dv : -1.0;
    int bi = al ? ei : -1;
#pragma unroll
    for (int s = 1; s < 64; s <<= 1) {
      double od = __shfl_xor(bd, s, 64);
      int oi = __shfl_xor(bi, s, 64);
      if (od > bd || (od == bd && oi > bi)) { bd = od; bi = oi; }
    }
    if (al && ei == bi) al = false;
  }
  unsigned long long msk = __ballot(al && ei != n);
  if (al) {
    if (ei == n) {
      idxOut[g * 20] = n;  // self first
    } else {
      int pos = 1 + __popcll(msk & ((1ull << lane) - 1ull));
      idxOut[g * 20 + pos] = ei;
    }
  }
  return true;
}

__launch_bounds__(512)
__global__ void k_knn(const float* __restrict__ x, int* __restrict__ idxOut) {
  __shared__ float xs[4096], ys[4096], zs[4096];
  int b = blockIdx.x >> 9;  // 512 blocks per batch, 8 rows per block
  const float* xb = x + b * 3 * 4096;
  for (int i = threadIdx.x; i < 4096; i += 512) {
    xs[i] = xb[i];
    ys[i] = xb[4096 + i];
    zs[i] = xb[8192 + i];
  }
  __syncthreads();
  int lane = threadIdx.x & 63;
  int n = ((blockIdx.x & 511) << 3) + (threadIdx.x >> 6);
  int g = b * 4096 + n;
  if (!knn_row<6>(xs, ys, zs, n, lane, g, true, idxOut))
    knn_row<24>(xs, ys, zs, n, lane, g, false, idxOut);
}

// ---------- K2: fused geometric features + aw + agg + conv ----------
// Block = 512 threads = 8 waves; wave p handles point p of the block's 8 points.
__launch_bounds__(512)
__global__ void k_main(const float* __restrict__ x, const float* __restrict__ feat,
                       const float* __restrict__ ftT, int useFtT,
                       const float* __restrict__ kern, const float* __restrict__ mlp_w,
                       const float* __restrict__ mlp_b, const float* __restrict__ cwt,
                       const float* __restrict__ conv_b, const int* __restrict__ idxIn,
                       float* __restrict__ out) {
  __shared__ __align__(16) unsigned short agg[8][2048];  // bf16 agg, also reused as f32 reduce scratch
  __shared__ float awL[8][20][16];
  __shared__ float f7L[8][20][7];
  __shared__ int idxL[8][20];

  int t = threadIdx.x;
  int p = t >> 6, lane = t & 63;
  int g = blockIdx.x * 8 + p;
  int b = g >> 12, n = g & 4095;
  const float* xb = x + b * 3 * 4096;

  // step 0: per-neighbor geometry + raw aw rows (lanes 0..19 of each wave)
  if (lane < 20) {
    int kk = idxIn[g * 20 + lane];
    idxL[p][lane] = kk;
    float qx = xb[n], qy = xb[4096 + n], qz = xb[8192 + n];
    float cx = xb[kk], cy = xb[4096 + kk], cz = xb[8192 + kk];
    float rx = cx - qx, ry = cy - qy, rz = cz - qz;
    float ds = sqrtf(rx * rx + ry * ry + rz * rz);
    f7L[p][lane][0] = qx;
    f7L[p][lane][1] = qy;
    f7L[p][lane][2] = qz;
    f7L[p][lane][3] = rx;
    f7L[p][lane][4] = ry;
    f7L[p][lane][5] = rz;
    f7L[p][lane][6] = ds;
#pragma unroll
    for (int s = 0; s < 16; ++s) {
      float dot = rx * kern[s] + ry * kern[16 + s] + rz * kern[32 + s];
      if (lane == 0 && s == 0) dot += 1.0f;
      awL[p][lane][s] = dot > 0.0f ? dot : 0.0f;
    }
  }
  __syncthreads();

  // step 1: aw normalization chain (128 threads: one per (point, s))
  if (t < 128) {
    int pp = t >> 4, s = t & 15;
    float sum = 0.0f;
#pragma unroll
    for (int k = 0; k < 20; ++k) sum += awL[pp][k][s];
    float inv1 = 1.0f / (sum + 1e-6f);
    float sum2 = 0.0f;
#pragma unroll
    for (int k = 0; k < 20; ++k) {
      float w = awL[pp][k][s] * inv1;
      sum2 += w * w;
    }
    float inv2 = 1.0f / (sum2 + 1e-6f);
#pragma unroll
    for (int k = 0; k < 20; ++k) {
      float w = awL[pp][k][s] * inv1;
      w = w * w * inv2;
      awL[pp][k][s] = (w > 0.1f) ? w : 0.0f;
    }
  }
  __syncthreads();

  // step 2: agg build. thread (p, c=lane) owns spiral row c and x_feats row c.
  {
    int c = lane;
    float fv[20];
    if (useFtT) {
#pragma unroll
      for (int k = 0; k < 20; ++k) fv[k] = ftT[(b * 4096 + idxL[p][k]) * 64 + c];
    } else {
      const float* fb = feat + (b * 64 + c) * 4096;
#pragma unroll
      for (int k = 0; k < 20; ++k) fv[k] = fb[idxL[p][k]];
    }
    float mw[7];
#pragma unroll
    for (int j = 0; j < 7; ++j) mw[j] = mlp_w[c * 7 + j];
    float mb = mlp_b[c];
    float xf[20];
#pragma unroll
    for (int k = 0; k < 20; ++k) {
      float s = mb;
#pragma unroll
      for (int j = 0; j < 7; ++j) s = fmaf(mw[j], f7L[p][k][j], s);
      xf[k] = s;
    }
    float acc1[16], acc2[16];
#pragma unroll
    for (int s = 0; s < 16; ++s) { acc1[s] = 0.0f; acc2[s] = 0.0f; }
#pragma unroll
    for (int k = 0; k < 20; ++k) {
      float a = fv[k], bx = xf[k];
#pragma unroll
      for (int s = 0; s < 16; ++s) {
        float w = awL[p][k][s];
        acc1[s] = fmaf(a, w, acc1[s]);
        acc2[s] = fmaf(bx, w, acc2[s]);
      }
    }
#pragma unroll
    for (int s = 0; s < 16; ++s) {
      agg[p][c * 16 + s] = f2bf(acc1[s]);
      agg[p][(64 + c) * 16 + s] = f2bf(acc2[s]);
    }
  }
  __syncthreads();

  // phase B: out[p][o] = conv_b[o] + sum_j cwt[j][o] * agg[p][j]
  // thread: og = t&15 (4 outputs), slice = t>>4 (32 j-slices of 64)
  int og = t & 15, slice = t >> 4;
  const float4* cwt4 = (const float4*)cwt;
  float acc[8][4];
#pragma unroll
  for (int pp = 0; pp < 8; ++pp)
#pragma unroll
    for (int q = 0; q < 4; ++q) acc[pp][q] = 0.0f;

  for (int jj = 0; jj < 64; ++jj) {
    int j = slice * 64 + jj;
    float4 w4 = cwt4[j * 16 + og];
#pragma unroll
    for (int pp = 0; pp < 8; ++pp) {
      float a = bf2f(agg[pp][j]);
      acc[pp][0] = fmaf(a, w4.x, acc[pp][0]);
      acc[pp][1] = fmaf(a, w4.y, acc[pp][1]);
      acc[pp][2] = fmaf(a, w4.z, acc[pp][2]);
      acc[pp][3] = fmaf(a, w4.w, acc[pp][3]);
    }
  }
  // reduce the 4 slices within each wave (lane bits 4,5)
#pragma unroll
  for (int pp = 0; pp < 8; ++pp)
#pragma unroll
    for (int q = 0; q < 4; ++q) {
      acc[pp][q] += __shfl_xor(acc[pp][q], 16, 64);
      acc[pp][q] += __shfl_xor(acc[pp][q], 32, 64);
    }
  __syncthreads();  // all agg reads done; safe to reuse LDS
  float* red = (float*)&agg[0][0];  // 16KB needed, 32KB available
  int w = t >> 6;
  if (((t >> 4) & 3) == 0) {
#pragma unroll
    for (int pp = 0; pp < 8; ++pp)
#pragma unroll
      for (int q = 0; q < 4; ++q)
        red[((w * 16 + og) * 8 + pp) * 4 + q] = acc[pp][q];
  }
  __syncthreads();
  // final cross-wave reduce + write: thread t -> (p = t>>6, o = t&63)
  {
    int pp = t >> 6, o = t & 63;
    float s = conv_b[o];
#pragma unroll
    for (int ww = 0; ww < 8; ++ww)
      s += red[((ww * 16 + (o >> 2)) * 8 + pp) * 4 + (o & 3)];
    int gg = blockIdx.x * 8 + pp;
    int bb = gg >> 12, nn = gg & 4095;
    out[(bb * 64 + o) * 4096 + nn] = s;
  }
}

// ---------- K3a: BN stats (one block per channel) ----------
__global__ void k_bnstats(const float* __restrict__ out, const float* __restrict__ gamma,
                          const float* __restrict__ beta, float* __restrict__ stats) {
  __shared__ double rs[256], rq[256];
  int o = blockIdx.x;
  double s = 0.0, q = 0.0;
  for (int b = 0; b < 8; ++b) {
    const float* p = out + (b * 64 + o) * 4096;
    for (int i = threadIdx.x; i < 4096; i += 256) {
      double v = (double)p[i];
      s += v;
      q += v * v;
    }
  }
  rs[threadIdx.x] = s;
  rq[threadIdx.x] = q;
  __syncthreads();
  for (int st = 128; st > 0; st >>= 1) {
    if ((int)threadIdx.x < st) {
      rs[threadIdx.x] += rs[threadIdx.x + st];
      rq[threadIdx.x] += rq[threadIdx.x + st];
    }
    __syncthreads();
  }
  if (threadIdx.x == 0) {
    double mean = rs[0] / 32768.0;
    double var = rq[0] / 32768.0 - mean * mean;
    double inv = 1.0 / sqrt(var + 1e-5);
    double sc = (double)gamma[o] * inv;
    stats[o * 2] = (float)sc;
    stats[o * 2 + 1] = (float)((double)beta[o] - mean * sc);
  }
}

// ---------- K3b: BN apply (in place) ----------
__global__ void k_bnapply(float* __restrict__ out, const float* __restrict__ stats) {
  int i = blockIdx.x * 256 + threadIdx.x;
  int o = (i >> 12) & 63;
  out[i] = fmaf(out[i], stats[o * 2], stats[o * 2 + 1]);
}

extern "C" void kernel_launch(void* const* d_in, const int* in_sizes, int n_in,
                              void* d_out, int out_size, void* d_ws, size_t ws_size,
                              hipStream_t stream) {
  const float* x = (const float*)d_in[0];
  const float* feat = (const float*)d_in[1];
  const float* kern = (const float*)d_in[2];
  const float* mlp_w = (const float*)d_in[3];
  const float* mlp_b = (const float*)d_in[4];
  const float* conv_w = (const float*)d_in[5];
  const float* conv_b = (const float*)d_in[6];
  const float* gamma = (const float*)d_in[7];
  const float* beta = (const float*)d_in[8];
  float* out = (float*)d_out;
  char* ws = (char*)d_ws;

  // workspace layout
  int* idx = (int*)ws;                          // 32768*20*4      = 2,621,440
  float* stats = (float*)(ws + 2621440);        // 64*2*4          = 512 (padded)
  float* cwt = (float*)(ws + 2625536);          // 2048*64*4       = 524,288
  float* ftT = (float*)(ws + 3149824);          // 8*4096*64*4     = 8,388,608
  int useFtT = (ws_size >= (size_t)(3149824 + 8388608)) ? 1 : 0;

  k_transpose_cw<<<512, 256, 0, stream>>>(conv_w, cwt);
  if (useFtT) k_transpose_ft<<<512, 256, 0, stream>>>(feat, ftT);
  k_knn<<<4096, 512, 0, stream>>>(x, idx);
  k_main<<<4096, 512, 0, stream>>>(x, feat, ftT, useFtT, kern, mlp_w, mlp_b, cwt,
                                   conv_b, idx, out);
  k_bnstats<<<64, 256, 0, stream>>>(out, gamma, beta, stats);
  k_bnapply<<<8192, 256, 0, stream>>>(out, stats);
}

// Round 3
// 364.311 us; speedup vs baseline: 5.3495x; 1.3661x over previous
//
#include <hip/hip_runtime.h>
#include <cfloat>
#include <math.h>

#define NB 8
#define NPT 4096
#define NC 64
#define KNN 20
#define KSZ 16
#define BPTS 16

typedef __attribute__((ext_vector_type(8))) short short8;
typedef __attribute__((ext_vector_type(4))) float f32x4;

// ---------- helpers ----------
__device__ __forceinline__ unsigned short f2bf(float f) {
  unsigned u = __float_as_uint(f);
  unsigned r = (u + 0x7fffu + ((u >> 16) & 1u)) >> 16;
  return (unsigned short)r;
}
__device__ __forceinline__ float bf2f(unsigned short h) {
  return __uint_as_float(((unsigned)h) << 16);
}

// ---------- K0a: conv_w [64][2048] -> Bpack bf16 in MFMA B-frag order ----------
// Bpack[((ks*4+nt)*64+lane)*8+j] = bf16(cw[o*2048+k]),
//   k = ks*32 + (lane>>4)*8 + j, o = nt*16 + (lane&15)
__global__ void k_pack_cw(const float* __restrict__ cw, unsigned short* __restrict__ bp) {
  int t = blockIdx.x * 256 + threadIdx.x;  // 131072
  int j = t & 7, lane = (t >> 3) & 63, nt = (t >> 9) & 3, ks = t >> 11;
  int k = ks * 32 + ((lane >> 4) << 3) + j;
  int o = nt * 16 + (lane & 15);
  bp[t] = f2bf(cw[o * 2048 + k]);
}

// ---------- K0b: feature [B][C][N] -> ftT [B][N][C] bf16 ----------
__global__ void k_transpose_ft(const float* __restrict__ f, unsigned short* __restrict__ ft) {
  __shared__ float tile[64][65];
  int b = blockIdx.x >> 6;
  int n0 = (blockIdx.x & 63) * 64;
  int lane = threadIdx.x & 63;
  int rr = threadIdx.x >> 6;  // 0..3
#pragma unroll
  for (int c0 = 0; c0 < 64; c0 += 4) {
    int c = c0 + rr;
    tile[c][lane] = f[(b * 64 + c) * 4096 + n0 + lane];
  }
  __syncthreads();
#pragma unroll
  for (int m0 = 0; m0 < 64; m0 += 4) {
    int nn = m0 + rr;
    ft[(b * 4096 + n0 + nn) * 64 + lane] = f2bf(tile[lane][nn]);
  }
}

// ---------- K1: KNN (unchanged from R2) ----------
__device__ __forceinline__ unsigned long long wave_min_u64(unsigned long long k) {
#pragma unroll
  for (int s = 1; s < 64; s <<= 1) {
    unsigned long long o = __shfl_xor(k, s, 64);
    k = (o < k) ? o : k;
  }
  return k;
}

template <int M>
__device__ __forceinline__ bool knn_row(const float* __restrict__ xs,
                                        const float* __restrict__ ys,
                                        const float* __restrict__ zs,
                                        int n, int lane, int g, bool check,
                                        int* __restrict__ idxOut) {
  float qx = xs[n], qy = ys[n], qz = zs[n];
  float v[M];
  int id[M];
#pragma unroll
  for (int r = 0; r < M; ++r) { v[r] = FLT_MAX; id[r] = 0x7fffffff; }

#pragma unroll 4
  for (int i = 0; i < 64; ++i) {
    int j = (i << 6) | lane;
    float dx = xs[j] - qx, dy = ys[j] - qy, dz = zs[j] - qz;
    float d2 = fmaf(dx, dx, fmaf(dy, dy, dz * dz));
    bool c[M];
#pragma unroll
    for (int r = 0; r < M; ++r) c[r] = d2 < v[r];
#pragma unroll
    for (int r = M - 1; r >= 1; --r) {
      v[r] = c[r - 1] ? v[r - 1] : (c[r] ? d2 : v[r]);
      id[r] = c[r - 1] ? id[r - 1] : (c[r] ? j : id[r]);
    }
    v[0] = c[0] ? d2 : v[0];
    id[0] = c[0] ? j : id[0];
  }
  float worst = v[M - 1];

  unsigned long long key = ((unsigned long long)__float_as_uint(v[0]) << 32) | (unsigned)id[0];
  unsigned long long ext = ~0ull;
  unsigned long long k = 0ull;
  for (int r = 0; r < 24; ++r) {
    k = wave_min_u64(key);
    if (lane == r) ext = k;
    if (key == k) {
#pragma unroll
      for (int q = 0; q < M - 1; ++q) { v[q] = v[q + 1]; id[q] = id[q + 1]; }
      v[M - 1] = FLT_MAX;
      id[M - 1] = 0x7fffffff;
      key = ((unsigned long long)__float_as_uint(v[0]) << 32) | (unsigned)id[0];
    }
  }
  if (check) {
    float t24 = __uint_as_float((unsigned)(k >> 32));
    if (__any(worst <= t24)) return false;
  }

  int ei = (int)(unsigned)(ext & 0xffffffffu);
  bool al = lane < 24;
  double dv = -1.0;
  if (al) {
    double dx = (double)xs[ei] - (double)qx;
    double dy = (double)ys[ei] - (double)qy;
    double dz = (double)zs[ei] - (double)qz;
    dv = dx * dx + dy * dy + dz * dz;
  }
#pragma unroll
  for (int r = 0; r < 4; ++r) {
    double bd = al ? dv : -1.0;
    int bi = al ? ei : -1;
#pragma unroll
    for (int s = 1; s < 64; s <<= 1) {
      double od = __shfl_xor(bd, s, 64);
      int oi = __shfl_xor(bi, s, 64);
      if (od > bd || (od == bd && oi > bi)) { bd = od; bi = oi; }
    }
    if (al && ei == bi) al = false;
  }
  unsigned long long msk = __ballot(al && ei != n);
  if (al) {
    if (ei == n) {
      idxOut[g * 20] = n;
    } else {
      int pos = 1 + __popcll(msk & ((1ull << lane) - 1ull));
      idxOut[g * 20 + pos] = ei;
    }
  }
  return true;
}

__launch_bounds__(512)
__global__ void k_knn(const float* __restrict__ x, int* __restrict__ idxOut) {
  __shared__ float xs[4096], ys[4096], zs[4096];
  int b = blockIdx.x >> 9;
  const float* xb = x + b * 3 * 4096;
  for (int i = threadIdx.x; i < 4096; i += 512) {
    xs[i] = xb[i];
    ys[i] = xb[4096 + i];
    zs[i] = xb[8192 + i];
  }
  __syncthreads();
  int lane = threadIdx.x & 63;
  int n = ((blockIdx.x & 511) << 3) + (threadIdx.x >> 6);
  int g = b * 4096 + n;
  if (!knn_row<6>(xs, ys, zs, n, lane, g, true, idxOut))
    knn_row<24>(xs, ys, zs, n, lane, g, false, idxOut);
}

// ---------- K2: fused features + aw + agg(bf16,swizzled) + MFMA conv ----------
__device__ __forceinline__ void mfma_pass(const unsigned short* aggp,
                                          const unsigned short* __restrict__ bp,
                                          int t, int lane, int ksbase, f32x4 acc[4]) {
  int w = t >> 6;
  int r = lane & 15;
  const char* rowbase = (const char*)aggp + r * 2048;
#pragma unroll
  for (int ks = 0; ks < 4; ++ks) {
    int ksl = w * 4 + ks;
    int off = (ksl * 64 + ((lane >> 4) << 4)) ^ ((r & 7) << 4);
    short8 af = *(const short8*)(rowbase + off);
#pragma unroll
    for (int nt = 0; nt < 4; ++nt) {
      int ksg = ksbase + ksl;
      short8 bf = *(const short8*)(bp + (((ksg * 4 + nt) * 64 + lane) << 3));
      acc[nt] = __builtin_amdgcn_mfma_f32_16x16x32_bf16(af, bf, acc[nt], 0, 0, 0);
    }
  }
}

__launch_bounds__(512, 4)
__global__ void k_main(const float* __restrict__ x, const float* __restrict__ feat,
                       const unsigned short* __restrict__ ftT, int useFtT,
                       const float* __restrict__ kern, const float* __restrict__ mlp_w,
                       const float* __restrict__ mlp_b, const unsigned short* __restrict__ bp,
                       const float* __restrict__ conv_b, const int* __restrict__ idxIn,
                       float* __restrict__ out) {
  __shared__ __align__(16) unsigned short agg[BPTS][1024];  // 32KB swizzled bf16; reused as f32 red
  __shared__ float awL[BPTS][20][16];                       // 20.5KB
  __shared__ float f7L[BPTS][20][7];                        // 9KB
  __shared__ int idxL[BPTS][20];

  int t = threadIdx.x;
  int lane = t & 63;
  int g0 = blockIdx.x * BPTS;
  int b = g0 >> 12, n0 = g0 & 4095;
  const float* xb = x + b * 3 * 4096;

  // ---- step 0: per-neighbor geometry + raw aw (16 pts x 20 nbrs on 512 thr) ----
  {
    int pt = t >> 5, slot = t & 31;
    if (slot < 20) {
      int n = n0 + pt;
      int kk = idxIn[(g0 + pt) * 20 + slot];
      idxL[pt][slot] = kk;
      float qx = xb[n], qy = xb[4096 + n], qz = xb[8192 + n];
      float rx = xb[kk] - qx, ry = xb[4096 + kk] - qy, rz = xb[8192 + kk] - qz;
      float ds = sqrtf(rx * rx + ry * ry + rz * rz);
      f7L[pt][slot][0] = qx;
      f7L[pt][slot][1] = qy;
      f7L[pt][slot][2] = qz;
      f7L[pt][slot][3] = rx;
      f7L[pt][slot][4] = ry;
      f7L[pt][slot][5] = rz;
      f7L[pt][slot][6] = ds;
#pragma unroll
      for (int s = 0; s < 16; ++s) {
        float dot = rx * kern[s] + ry * kern[16 + s] + rz * kern[32 + s];
        if (slot == 0 && s == 0) dot += 1.0f;
        awL[pt][slot][s] = dot > 0.0f ? dot : 0.0f;
      }
    }
  }
  __syncthreads();

  // ---- step 1: aw normalization chain (256 thr: one per (pt,s)) ----
  if (t < 256) {
    int pp = t >> 4, s = t & 15;
    float sum = 0.0f;
#pragma unroll
    for (int k = 0; k < 20; ++k) sum += awL[pp][k][s];
    float inv1 = 1.0f / (sum + 1e-6f);
    float sum2 = 0.0f;
#pragma unroll
    for (int k = 0; k < 20; ++k) {
      float w = awL[pp][k][s] * inv1;
      sum2 += w * w;
    }
    float inv2 = 1.0f / (sum2 + 1e-6f);
#pragma unroll
    for (int k = 0; k < 20; ++k) {
      float w = awL[pp][k][s] * inv1;
      w = w * w * inv2;
      awL[pp][k][s] = (w > 0.1f) ? w : 0.0f;
    }
  }
  __syncthreads();

  f32x4 acc[4];
#pragma unroll
  for (int nt = 0; nt < 4; ++nt) acc[nt] = (f32x4){0.f, 0.f, 0.f, 0.f};
  int c = lane;

  // ---- phase A1: spiral half (K = 0..1023), agg[pt][c*16+s] ----
#pragma unroll
  for (int half = 0; half < 2; ++half) {
    int pt = ((t >> 6) << 1) + half;
    float fv[20];
    if (useFtT) {
#pragma unroll
      for (int k = 0; k < 20; ++k) fv[k] = bf2f(ftT[(b * 4096 + idxL[pt][k]) * 64 + c]);
    } else {
      const float* fb = feat + (b * 64 + c) * 4096;
#pragma unroll
      for (int k = 0; k < 20; ++k) fv[k] = fb[idxL[pt][k]];
    }
    float a1[16];
#pragma unroll
    for (int s = 0; s < 16; ++s) a1[s] = 0.0f;
#pragma unroll
    for (int k = 0; k < 20; ++k) {
      float a = fv[k];
#pragma unroll
      for (int s = 0; s < 16; ++s) a1[s] = fmaf(a, awL[pt][k][s], a1[s]);
    }
    __align__(16) unsigned short tmp[16];
#pragma unroll
    for (int s = 0; s < 16; ++s) tmp[s] = f2bf(a1[s]);
    char* rb = (char*)&agg[pt][0];
    int sw = (pt & 7) << 4;
    *(uint4*)(rb + ((c * 32) ^ sw)) = *(uint4*)&tmp[0];
    *(uint4*)(rb + ((c * 32 + 16) ^ sw)) = *(uint4*)&tmp[8];
  }
  __syncthreads();
  mfma_pass(&agg[0][0], bp, t, lane, 0, acc);
  __syncthreads();

  // ---- phase A2: x_feats half (K = 1024..2047) ----
#pragma unroll
  for (int half = 0; half < 2; ++half) {
    int pt = ((t >> 6) << 1) + half;
    float mw[7];
#pragma unroll
    for (int j = 0; j < 7; ++j) mw[j] = mlp_w[c * 7 + j];
    float mb = mlp_b[c];
    float xf[20];
#pragma unroll
    for (int k = 0; k < 20; ++k) {
      float s = mb;
#pragma unroll
      for (int j = 0; j < 7; ++j) s = fmaf(mw[j], f7L[pt][k][j], s);
      xf[k] = s;
    }
    float a1[16];
#pragma unroll
    for (int s = 0; s < 16; ++s) a1[s] = 0.0f;
#pragma unroll
    for (int k = 0; k < 20; ++k) {
      float a = xf[k];
#pragma unroll
      for (int s = 0; s < 16; ++s) a1[s] = fmaf(a, awL[pt][k][s], a1[s]);
    }
    __align__(16) unsigned short tmp[16];
#pragma unroll
    for (int s = 0; s < 16; ++s) tmp[s] = f2bf(a1[s]);
    char* rb = (char*)&agg[pt][0];
    int sw = (pt & 7) << 4;
    *(uint4*)(rb + ((c * 32) ^ sw)) = *(uint4*)&tmp[0];
    *(uint4*)(rb + ((c * 32 + 16) ^ sw)) = *(uint4*)&tmp[8];
  }
  __syncthreads();
  mfma_pass(&agg[0][0], bp, t, lane, 32, acc);
  __syncthreads();  // before reusing agg as red

  // ---- cross-wave reduce (red reuses agg region, o-index XOR swizzle) ----
  float* red = (float*)&agg[0][0];  // 8*16*64*4 = 32KB
  {
    int w = t >> 6;
#pragma unroll
    for (int nt = 0; nt < 4; ++nt)
#pragma unroll
      for (int r = 0; r < 4; ++r) {
        int pt = ((lane >> 4) << 2) + r;
        int o = nt * 16 + (lane & 15);
        red[(w * 16 + pt) * 64 + (o ^ ((pt & 7) << 2))] = acc[nt][r];
      }
  }
  __syncthreads();
#pragma unroll
  for (int rep = 0; rep < 2; ++rep) {
    int u = rep * 512 + t;
    int pt = u & 15, o = u >> 4;
    float s = conv_b[o];
#pragma unroll
    for (int w = 0; w < 8; ++w) s += red[(w * 16 + pt) * 64 + (o ^ ((pt & 7) << 2))];
    out[(b * 64 + o) * 4096 + n0 + pt] = s;
  }
}

// ---------- K3a: BN stats ----------
__global__ void k_bnstats(const float* __restrict__ out, const float* __restrict__ gamma,
                          const float* __restrict__ beta, float* __restrict__ stats) {
  __shared__ double rs[256], rq[256];
  int o = blockIdx.x;
  double s = 0.0, q = 0.0;
  for (int b = 0; b < 8; ++b) {
    const float* p = out + (b * 64 + o) * 4096;
    for (int i = threadIdx.x; i < 4096; i += 256) {
      double v = (double)p[i];
      s += v;
      q += v * v;
    }
  }
  rs[threadIdx.x] = s;
  rq[threadIdx.x] = q;
  __syncthreads();
  for (int st = 128; st > 0; st >>= 1) {
    if ((int)threadIdx.x < st) {
      rs[threadIdx.x] += rs[threadIdx.x + st];
      rq[threadIdx.x] += rq[threadIdx.x + st];
    }
    __syncthreads();
  }
  if (threadIdx.x == 0) {
    double mean = rs[0] / 32768.0;
    double var = rq[0] / 32768.0 - mean * mean;
    double inv = 1.0 / sqrt(var + 1e-5);
    double sc = (double)gamma[o] * inv;
    stats[o * 2] = (float)sc;
    stats[o * 2 + 1] = (float)((double)beta[o] - mean * sc);
  }
}

// ---------- K3b: BN apply ----------
__global__ void k_bnapply(float* __restrict__ out, const float* __restrict__ stats) {
  int i = blockIdx.x * 256 + threadIdx.x;
  int o = (i >> 12) & 63;
  out[i] = fmaf(out[i], stats[o * 2], stats[o * 2 + 1]);
}

extern "C" void kernel_launch(void* const* d_in, const int* in_sizes, int n_in,
                              void* d_out, int out_size, void* d_ws, size_t ws_size,
                              hipStream_t stream) {
  const float* x = (const float*)d_in[0];
  const float* feat = (const float*)d_in[1];
  const float* kern = (const float*)d_in[2];
  const float* mlp_w = (const float*)d_in[3];
  const float* mlp_b = (const float*)d_in[4];
  const float* conv_w = (const float*)d_in[5];
  const float* conv_b = (const float*)d_in[6];
  const float* gamma = (const float*)d_in[7];
  const float* beta = (const float*)d_in[8];
  float* out = (float*)d_out;
  char* ws = (char*)d_ws;

  // workspace layout
  int* idx = (int*)ws;                                   // 2,621,440 B
  float* stats = (float*)(ws + 2621440);                 // 4 KB pad
  unsigned short* bpk = (unsigned short*)(ws + 2625536); // 262,144 B
  unsigned short* ftT = (unsigned short*)(ws + 2887680); // 4,194,304 B
  int useFtT = (ws_size >= (size_t)(2887680 + 4194304)) ? 1 : 0;

  k_pack_cw<<<512, 256, 0, stream>>>(conv_w, bpk);
  if (useFtT) k_transpose_ft<<<512, 256, 0, stream>>>(feat, ftT);
  k_knn<<<4096, 512, 0, stream>>>(x, idx);
  k_main<<<2048, 512, 0, stream>>>(x, feat, ftT, useFtT, kern, mlp_w, mlp_b, bpk,
                                   conv_b, idx, out);
  k_bnstats<<<64, 256, 0, stream>>>(out, gamma, beta, stats);
  k_bnapply<<<8192, 256, 0, stream>>>(out, stats);
}

// Round 4
// 257.336 us; speedup vs baseline: 7.5733x; 1.4157x over previous
//
#include <hip/hip_runtime.h>
#include <cfloat>
#include <math.h>

#define NB 8
#define NPT 4096
#define NC 64
#define KNN 20
#define KSZ 16
#define BPTS 16

typedef __attribute__((ext_vector_type(8))) short short8;
typedef __attribute__((ext_vector_type(4))) float f32x4;

// ---------- helpers ----------
__device__ __forceinline__ unsigned short f2bf(float f) {
  unsigned u = __float_as_uint(f);
  unsigned r = (u + 0x7fffu + ((u >> 16) & 1u)) >> 16;
  return (unsigned short)r;
}
__device__ __forceinline__ float bf2f(unsigned short h) {
  return __uint_as_float(((unsigned)h) << 16);
}

// ---------- K0a: conv_w [64][2048] -> Bpack bf16 in MFMA B-frag order ----------
__global__ void k_pack_cw(const float* __restrict__ cw, unsigned short* __restrict__ bp) {
  int t = blockIdx.x * 256 + threadIdx.x;  // 131072
  int j = t & 7, lane = (t >> 3) & 63, nt = (t >> 9) & 3, ks = t >> 11;
  int k = ks * 32 + ((lane >> 4) << 3) + j;
  int o = nt * 16 + (lane & 15);
  bp[t] = f2bf(cw[o * 2048 + k]);
}

// ---------- K0b: feature [B][C][N] -> ftT [B][N][C] bf16 ----------
__global__ void k_transpose_ft(const float* __restrict__ f, unsigned short* __restrict__ ft) {
  __shared__ float tile[64][65];
  int b = blockIdx.x >> 6;
  int n0 = (blockIdx.x & 63) * 64;
  int lane = threadIdx.x & 63;
  int rr = threadIdx.x >> 6;  // 0..3
#pragma unroll
  for (int c0 = 0; c0 < 64; c0 += 4) {
    int c = c0 + rr;
    tile[c][lane] = f[(b * 64 + c) * 4096 + n0 + lane];
  }
  __syncthreads();
#pragma unroll
  for (int m0 = 0; m0 < 64; m0 += 4) {
    int nn = m0 + rr;
    ft[(b * 4096 + n0 + nn) * 64 + lane] = f2bf(tile[lane][nn]);
  }
}

// ---------- K1: KNN v3 ----------
// One wave per row. Pass1: per-lane min of 64 candidates (d' = xx_j - 2 q.c).
// Bitonic-sort the 64 lane minima -> T = 24th smallest (>= f32 rank-24 of row).
// Pass2: ballot-collect all j with d' <= T, compact into lanes via ds_permute.
// Exact f64 lex re-rank (rank-by-count), keep rank<20, self at slot 0.
// Guarded fallback to full exact path (never taken in practice).

__device__ __noinline__ void knn_full(const float4* __restrict__ pts, int n, int lane,
                                      int g, int* __restrict__ idxOut) {
  const int M = 24;
  float4 qp = pts[n];
  float qx = qp.x, qy = qp.y, qz = qp.z;
  float v[M];
  int id[M];
#pragma unroll
  for (int r = 0; r < M; ++r) { v[r] = FLT_MAX; id[r] = 0x7fffffff; }
  for (int i = 0; i < 64; ++i) {
    int j = (i << 6) | lane;
    float4 p = pts[j];
    float dx = p.x - qx, dy = p.y - qy, dz = p.z - qz;
    float d2 = fmaf(dx, dx, fmaf(dy, dy, dz * dz));
    bool c[M];
#pragma unroll
    for (int r = 0; r < M; ++r) c[r] = d2 < v[r];
#pragma unroll
    for (int r = M - 1; r >= 1; --r) {
      v[r] = c[r - 1] ? v[r - 1] : (c[r] ? d2 : v[r]);
      id[r] = c[r - 1] ? id[r - 1] : (c[r] ? j : id[r]);
    }
    v[0] = c[0] ? d2 : v[0];
    id[0] = c[0] ? j : id[0];
  }
  unsigned long long key = ((unsigned long long)__float_as_uint(v[0]) << 32) | (unsigned)id[0];
  unsigned long long ext = ~0ull;
  for (int r = 0; r < 24; ++r) {
    unsigned long long k = key;
#pragma unroll
    for (int s = 1; s < 64; s <<= 1) {
      unsigned long long o = __shfl_xor(k, s, 64);
      k = (o < k) ? o : k;
    }
    if (lane == r) ext = k;
    if (key == k) {
#pragma unroll
      for (int q = 0; q < M - 1; ++q) { v[q] = v[q + 1]; id[q] = id[q + 1]; }
      v[M - 1] = FLT_MAX;
      id[M - 1] = 0x7fffffff;
      key = ((unsigned long long)__float_as_uint(v[0]) << 32) | (unsigned)id[0];
    }
  }
  int ei = (int)(unsigned)(ext & 0xffffffffu);
  bool al = lane < 24;
  double dv = -1.0;
  if (al) {
    float4 p = pts[ei];
    double dx = (double)p.x - (double)qx;
    double dy = (double)p.y - (double)qy;
    double dz = (double)p.z - (double)qz;
    dv = dx * dx + dy * dy + dz * dz;
  }
#pragma unroll
  for (int r = 0; r < 4; ++r) {
    double bd = al ? dv : -1.0;
    int bi = al ? ei : -1;
#pragma unroll
    for (int s = 1; s < 64; s <<= 1) {
      double od = __shfl_xor(bd, s, 64);
      int oi = __shfl_xor(bi, s, 64);
      if (od > bd || (od == bd && oi > bi)) { bd = od; bi = oi; }
    }
    if (al && ei == bi) al = false;
  }
  unsigned long long msk = __ballot(al && ei != n);
  if (al) {
    if (ei == n) {
      idxOut[g * 20] = n;
    } else {
      int pos = 1 + __popcll(msk & ((1ull << lane) - 1ull));
      idxOut[g * 20 + pos] = ei;
    }
  }
}

__launch_bounds__(1024, 8)
__global__ void k_knn(const float* __restrict__ x, int* __restrict__ idxOut) {
  __shared__ float4 pts[4096];  // 64KB: (x,y,z,xx)
  int b = blockIdx.x >> 8;
  const float* xb = x + b * 3 * 4096;
  for (int i = threadIdx.x; i < 4096; i += 1024) {
    float px = xb[i], py = xb[4096 + i], pz = xb[8192 + i];
    pts[i] = make_float4(px, py, pz, fmaf(px, px, fmaf(py, py, pz * pz)));
  }
  __syncthreads();

  int lane = threadIdx.x & 63;
  int n = ((blockIdx.x & 255) << 4) + (threadIdx.x >> 6);
  int g = b * 4096 + n;

  float4 qp = pts[n];
  float m2x = -2.0f * qp.x, m2y = -2.0f * qp.y, m2z = -2.0f * qp.z;

  // ---- pass 1: per-lane min ----
  float v = FLT_MAX;
#pragma unroll 4
  for (int i = 0; i < 64; ++i) {
    float4 p = pts[(i << 6) | lane];
    float d = fmaf(m2z, p.z, fmaf(m2y, p.y, fmaf(m2x, p.x, p.w)));
    v = fminf(v, d);
  }

  // ---- bitonic sort 64 lane minima (ascending by lane) ----
#pragma unroll
  for (int k = 2; k <= 64; k <<= 1) {
#pragma unroll
    for (int j = k >> 1; j > 0; j >>= 1) {
      float o = __shfl_xor(v, j, 64);
      bool up = ((lane & k) == 0);
      bool lower = ((lane & j) == 0);
      float mn = fminf(v, o), mx = fmaxf(v, o);
      v = (up == lower) ? mn : mx;
    }
  }
  float T = __shfl(v, 23, 64);  // >= f32 rank-24 of the full row

  // ---- pass 2: collect all d' <= T, compact via ds_permute ----
  int ei = -1;
  int base = 0;
  bool ovf = false;
#pragma unroll 2
  for (int i = 0; i < 64; ++i) {
    int j = (i << 6) | lane;
    float4 p = pts[j];
    float d = fmaf(m2z, p.z, fmaf(m2y, p.y, fmaf(m2x, p.x, p.w)));
    bool pred = (d <= T);
    unsigned long long mask = __ballot(pred);
    if (mask) {
      int cnt = __popcll(mask);
      if (base + cnt > 63) {
        ovf = true;
      } else {
        int dst = pred ? (base + __popcll(mask & ((1ull << lane) - 1ull))) : 63;
        int got = __builtin_amdgcn_ds_permute(dst << 2, j);
        bool recv = (lane >= base) && (lane < base + cnt);
        ei = recv ? got : ei;
      }
      base += cnt;
    }
  }

  bool ok = !ovf;
  if (ok) {
    // ---- exact f64 lex rank-by-count over the |S|=base candidates ----
    bool act = lane < base;
    double dm = 1e300;
    if (act) {
      float4 p = pts[ei];
      double dx = (double)p.x - (double)qp.x;
      double dy = (double)p.y - (double)qp.y;
      double dz = (double)p.z - (double)qp.z;
      dm = dx * dx + dy * dy + dz * dz;
    }
    int rank = 0;
    for (int r = 0; r < base; ++r) {
      double dr = __shfl(dm, r, 64);
      int ir = __shfl(ei, r, 64);
      bool less = (dr < dm) || (dr == dm && ir < ei);
      rank += less ? 1 : 0;
    }
    bool keep = act && (rank < 20);
    bool isSelf = keep && (ei == n);
    unsigned long long smask = __ballot(isSelf);
    ok = (smask != 0ull);
    if (ok) {
      if (isSelf) idxOut[g * 20] = n;
      unsigned long long msk = __ballot(keep && !isSelf);
      if (keep && !isSelf) {
        int pos = 1 + __popcll(msk & ((1ull << lane) - 1ull));
        idxOut[g * 20 + pos] = ei;
      }
    }
  }
  if (!ok) knn_full(pts, n, lane, g, idxOut);
}

// ---------- K2: fused features + aw + agg(bf16,swizzled) + MFMA conv ----------
__device__ __forceinline__ void mfma_pass(const unsigned short* aggp,
                                          const unsigned short* __restrict__ bp,
                                          int t, int lane, int ksbase, f32x4 acc[4]) {
  int w = t >> 6;
  int r = lane & 15;
  const char* rowbase = (const char*)aggp + r * 2048;
#pragma unroll
  for (int ks = 0; ks < 4; ++ks) {
    int ksl = w * 4 + ks;
    int off = (ksl * 64 + ((lane >> 4) << 4)) ^ ((r & 7) << 4);
    short8 af = *(const short8*)(rowbase + off);
#pragma unroll
    for (int nt = 0; nt < 4; ++nt) {
      int ksg = ksbase + ksl;
      short8 bf = *(const short8*)(bp + (((ksg * 4 + nt) * 64 + lane) << 3));
      acc[nt] = __builtin_amdgcn_mfma_f32_16x16x32_bf16(af, bf, acc[nt], 0, 0, 0);
    }
  }
}

__launch_bounds__(512, 4)
__global__ void k_main(const float* __restrict__ x, const float* __restrict__ feat,
                       const unsigned short* __restrict__ ftT, int useFtT,
                       const float* __restrict__ kern, const float* __restrict__ mlp_w,
                       const float* __restrict__ mlp_b, const unsigned short* __restrict__ bp,
                       const float* __restrict__ conv_b, const int* __restrict__ idxIn,
                       float* __restrict__ out) {
  __shared__ __align__(16) unsigned short agg[BPTS][1024];  // 32KB swizzled bf16; reused as f32 red
  __shared__ float awL[BPTS][20][16];                       // 20.5KB
  __shared__ float f7L[BPTS][20][7];                        // 9KB
  __shared__ int idxL[BPTS][20];

  int t = threadIdx.x;
  int lane = t & 63;
  int g0 = blockIdx.x * BPTS;
  int b = g0 >> 12, n0 = g0 & 4095;
  const float* xb = x + b * 3 * 4096;

  // ---- step 0: per-neighbor geometry + raw aw (16 pts x 20 nbrs on 512 thr) ----
  {
    int pt = t >> 5, slot = t & 31;
    if (slot < 20) {
      int n = n0 + pt;
      int kk = idxIn[(g0 + pt) * 20 + slot];
      idxL[pt][slot] = kk;
      float qx = xb[n], qy = xb[4096 + n], qz = xb[8192 + n];
      float rx = xb[kk] - qx, ry = xb[4096 + kk] - qy, rz = xb[8192 + kk] - qz;
      float ds = sqrtf(rx * rx + ry * ry + rz * rz);
      f7L[pt][slot][0] = qx;
      f7L[pt][slot][1] = qy;
      f7L[pt][slot][2] = qz;
      f7L[pt][slot][3] = rx;
      f7L[pt][slot][4] = ry;
      f7L[pt][slot][5] = rz;
      f7L[pt][slot][6] = ds;
#pragma unroll
      for (int s = 0; s < 16; ++s) {
        float dot = rx * kern[s] + ry * kern[16 + s] + rz * kern[32 + s];
        if (slot == 0 && s == 0) dot += 1.0f;
        awL[pt][slot][s] = dot > 0.0f ? dot : 0.0f;
      }
    }
  }
  __syncthreads();

  // ---- step 1: aw normalization chain (256 thr: one per (pt,s)) ----
  if (t < 256) {
    int pp = t >> 4, s = t & 15;
    float sum = 0.0f;
#pragma unroll
    for (int k = 0; k < 20; ++k) sum += awL[pp][k][s];
    float inv1 = 1.0f / (sum + 1e-6f);
    float sum2 = 0.0f;
#pragma unroll
    for (int k = 0; k < 20; ++k) {
      float w = awL[pp][k][s] * inv1;
      sum2 += w * w;
    }
    float inv2 = 1.0f / (sum2 + 1e-6f);
#pragma unroll
    for (int k = 0; k < 20; ++k) {
      float w = awL[pp][k][s] * inv1;
      w = w * w * inv2;
      awL[pp][k][s] = (w > 0.1f) ? w : 0.0f;
    }
  }
  __syncthreads();

  f32x4 acc[4];
#pragma unroll
  for (int nt = 0; nt < 4; ++nt) acc[nt] = (f32x4){0.f, 0.f, 0.f, 0.f};
  int c = lane;

  // ---- phase A1: spiral half (K = 0..1023) ----
#pragma unroll
  for (int half = 0; half < 2; ++half) {
    int pt = ((t >> 6) << 1) + half;
    float fv[20];
    if (useFtT) {
#pragma unroll
      for (int k = 0; k < 20; ++k) fv[k] = bf2f(ftT[(b * 4096 + idxL[pt][k]) * 64 + c]);
    } else {
      const float* fb = feat + (b * 64 + c) * 4096;
#pragma unroll
      for (int k = 0; k < 20; ++k) fv[k] = fb[idxL[pt][k]];
    }
    float a1[16];
#pragma unroll
    for (int s = 0; s < 16; ++s) a1[s] = 0.0f;
#pragma unroll
    for (int k = 0; k < 20; ++k) {
      float a = fv[k];
#pragma unroll
      for (int s = 0; s < 16; ++s) a1[s] = fmaf(a, awL[pt][k][s], a1[s]);
    }
    __align__(16) unsigned short tmp[16];
#pragma unroll
    for (int s = 0; s < 16; ++s) tmp[s] = f2bf(a1[s]);
    char* rb = (char*)&agg[pt][0];
    int sw = (pt & 7) << 4;
    *(uint4*)(rb + ((c * 32) ^ sw)) = *(uint4*)&tmp[0];
    *(uint4*)(rb + ((c * 32 + 16) ^ sw)) = *(uint4*)&tmp[8];
  }
  __syncthreads();
  mfma_pass(&agg[0][0], bp, t, lane, 0, acc);
  __syncthreads();

  // ---- phase A2: x_feats half (K = 1024..2047) ----
#pragma unroll
  for (int half = 0; half < 2; ++half) {
    int pt = ((t >> 6) << 1) + half;
    float mw[7];
#pragma unroll
    for (int j = 0; j < 7; ++j) mw[j] = mlp_w[c * 7 + j];
    float mb = mlp_b[c];
    float xf[20];
#pragma unroll
    for (int k = 0; k < 20; ++k) {
      float s = mb;
#pragma unroll
      for (int j = 0; j < 7; ++j) s = fmaf(mw[j], f7L[pt][k][j], s);
      xf[k] = s;
    }
    float a1[16];
#pragma unroll
    for (int s = 0; s < 16; ++s) a1[s] = 0.0f;
#pragma unroll
    for (int k = 0; k < 20; ++k) {
      float a = xf[k];
#pragma unroll
      for (int s = 0; s < 16; ++s) a1[s] = fmaf(a, awL[pt][k][s], a1[s]);
    }
    __align__(16) unsigned short tmp[16];
#pragma unroll
    for (int s = 0; s < 16; ++s) tmp[s] = f2bf(a1[s]);
    char* rb = (char*)&agg[pt][0];
    int sw = (pt & 7) << 4;
    *(uint4*)(rb + ((c * 32) ^ sw)) = *(uint4*)&tmp[0];
    *(uint4*)(rb + ((c * 32 + 16) ^ sw)) = *(uint4*)&tmp[8];
  }
  __syncthreads();
  mfma_pass(&agg[0][0], bp, t, lane, 32, acc);
  __syncthreads();  // before reusing agg as red

  // ---- cross-wave reduce ----
  float* red = (float*)&agg[0][0];  // 32KB
  {
    int w = t >> 6;
#pragma unroll
    for (int nt = 0; nt < 4; ++nt)
#pragma unroll
      for (int r = 0; r < 4; ++r) {
        int pt = ((lane >> 4) << 2) + r;
        int o = nt * 16 + (lane & 15);
        red[(w * 16 + pt) * 64 + (o ^ ((pt & 7) << 2))] = acc[nt][r];
      }
  }
  __syncthreads();
#pragma unroll
  for (int rep = 0; rep < 2; ++rep) {
    int u = rep * 512 + t;
    int pt = u & 15, o = u >> 4;
    float s = conv_b[o];
#pragma unroll
    for (int w = 0; w < 8; ++w) s += red[(w * 16 + pt) * 64 + (o ^ ((pt & 7) << 2))];
    out[(b * 64 + o) * 4096 + n0 + pt] = s;
  }
}

// ---------- K3a: BN stats ----------
__global__ void k_bnstats(const float* __restrict__ out, const float* __restrict__ gamma,
                          const float* __restrict__ beta, float* __restrict__ stats) {
  __shared__ double rs[256], rq[256];
  int o = blockIdx.x;
  double s = 0.0, q = 0.0;
  for (int b = 0; b < 8; ++b) {
    const float* p = out + (b * 64 + o) * 4096;
    for (int i = threadIdx.x; i < 4096; i += 256) {
      double v = (double)p[i];
      s += v;
      q += v * v;
    }
  }
  rs[threadIdx.x] = s;
  rq[threadIdx.x] = q;
  __syncthreads();
  for (int st = 128; st > 0; st >>= 1) {
    if ((int)threadIdx.x < st) {
      rs[threadIdx.x] += rs[threadIdx.x + st];
      rq[threadIdx.x] += rq[threadIdx.x + st];
    }
    __syncthreads();
  }
  if (threadIdx.x == 0) {
    double mean = rs[0] / 32768.0;
    double var = rq[0] / 32768.0 - mean * mean;
    double inv = 1.0 / sqrt(var + 1e-5);
    double sc = (double)gamma[o] * inv;
    stats[o * 2] = (float)sc;
    stats[o * 2 + 1] = (float)((double)beta[o] - mean * sc);
  }
}

// ---------- K3b: BN apply ----------
__global__ void k_bnapply(float* __restrict__ out, const float* __restrict__ stats) {
  int i = blockIdx.x * 256 + threadIdx.x;
  int o = (i >> 12) & 63;
  out[i] = fmaf(out[i], stats[o * 2], stats[o * 2 + 1]);
}

extern "C" void kernel_launch(void* const* d_in, const int* in_sizes, int n_in,
                              void* d_out, int out_size, void* d_ws, size_t ws_size,
                              hipStream_t stream) {
  const float* x = (const float*)d_in[0];
  const float* feat = (const float*)d_in[1];
  const float* kern = (const float*)d_in[2];
  const float* mlp_w = (const float*)d_in[3];
  const float* mlp_b = (const float*)d_in[4];
  const float* conv_w = (const float*)d_in[5];
  const float* conv_b = (const float*)d_in[6];
  const float* gamma = (const float*)d_in[7];
  const float* beta = (const float*)d_in[8];
  float* out = (float*)d_out;
  char* ws = (char*)d_ws;

  // workspace layout
  int* idx = (int*)ws;                                   // 2,621,440 B
  float* stats = (float*)(ws + 2621440);                 // 4 KB pad
  unsigned short* bpk = (unsigned short*)(ws + 2625536); // 262,144 B
  unsigned short* ftT = (unsigned short*)(ws + 2887680); // 4,194,304 B
  int useFtT = (ws_size >= (size_t)(2887680 + 4194304)) ? 1 : 0;

  k_pack_cw<<<512, 256, 0, stream>>>(conv_w, bpk);
  if (useFtT) k_transpose_ft<<<512, 256, 0, stream>>>(feat, ftT);
  k_knn<<<2048, 1024, 0, stream>>>(x, idx);
  k_main<<<2048, 512, 0, stream>>>(x, feat, ftT, useFtT, kern, mlp_w, mlp_b, bpk,
                                   conv_b, idx, out);
  k_bnstats<<<64, 256, 0, stream>>>(out, gamma, beta, stats);
  k_bnapply<<<8192, 256, 0, stream>>>(out, stats);
}